// Round 10
// baseline (1138.782 us; speedup 1.0000x reference)
//
#include <hip/hip_runtime.h>
#include <math.h>

#define B_SZ 2
#define N_SEQ 2048
#define DM 1024
#define H_HEADS 16
#define DH 64
#define KC 32
#define TOPK 100
#define TQ 16
#define LCAP 448
#define NCHUNK 4
#define BH_PER_CHUNK 8
#define NTILES 136   // 16*17/2 lower-triangular 128x128 tiles
#define TILE_ELEMS 16384

typedef _Float16 half2_t __attribute__((ext_vector_type(2)));
typedef _Float16 half4_t __attribute__((ext_vector_type(4)));
typedef _Float16 half8_t __attribute__((ext_vector_type(8)));
typedef float floatx4 __attribute__((ext_vector_type(4)));

// ---------- helpers ----------
__device__ __forceinline__ unsigned short h2us(_Float16 h) {
  unsigned short u; __builtin_memcpy(&u, &h, 2); return u;
}
__device__ __forceinline__ _Float16 us2h(unsigned short u) {
  _Float16 h; __builtin_memcpy(&h, &u, 2); return h;
}
__device__ __forceinline__ unsigned okey16(unsigned short us) {
  return (us & 0x8000u) ? (unsigned)(unsigned short)~us
                        : (unsigned)(us | 0x8000u);
}

// async global->LDS, 16 B per lane; lds_base must be wave-uniform
__device__ __forceinline__ void stage16(const _Float16* g, _Float16* lds_base,
                                        int lane) {
#if __has_builtin(__builtin_amdgcn_global_load_lds)
  __builtin_amdgcn_global_load_lds(
      (const __attribute__((address_space(1))) void*)g,
      (__attribute__((address_space(3))) void*)lds_base, 16, 0, 0);
#else
  *(half8_t*)(lds_base + lane * 8) = *(const half8_t*)g;
#endif
}

// ---------- constants: Riemann-zero weights ----------
__global__ void const_kernel(float* __restrict__ wre, float* __restrict__ wim) {
  __shared__ double g0s;
  const int k = threadIdx.x;  // 32 threads
  const double PI = 3.14159265358979323846;
  const double E_ = 2.71828182845904523536;
  double n = (double)(k + 1);
  double t = 10.0 + 6.0 * n;
  for (int it = 0; it < 60; ++it) {
    double f  = t / (2.0 * PI) * log(t / (2.0 * PI * E_)) - (n - 0.875);
    double fp = log(t / (2.0 * PI)) / (2.0 * PI);
    t = t - f / fp;
  }
  if (k == 0) g0s = t;
  __syncthreads();
  double g = t / g0s;
  double denom = 0.25 + g * g;
  wre[k] = (float)(0.5 / denom);
  wim[k] = (float)(-g / denom);
}

// ---------- RoPE tables ----------
__global__ __launch_bounds__(256) void rope_kernel(float* __restrict__ cosT,
                                                   float* __restrict__ sinT) {
  int idx = blockIdx.x * 256 + threadIdx.x;  // 65536 = 2048*32
  int kk = idx & 31, n = idx >> 5;
  double inv_freq = pow(10000.0, -(double)kk / 32.0);
  double ph = (double)n * inv_freq;
  cosT[idx] = (float)cos(ph);
  sinT[idx] = (float)sin(ph);
}

// ---------- cast x fp32 -> fp16 ----------
__global__ __launch_bounds__(256) void cast_x(const float* __restrict__ x,
                                              _Float16* __restrict__ xh) {
  int idx = blockIdx.x * 256 + threadIdx.x;
  float4 v = ((const float4*)x)[idx];
  half4_t h;
  h[0] = (_Float16)v.x; h[1] = (_Float16)v.y;
  h[2] = (_Float16)v.z; h[3] = (_Float16)v.w;
  ((half4_t*)xh)[idx] = h;
}

// ---------- transpose-cast W (fp32 [k][n]) -> Wt (fp16 [n][k]) ----------
__global__ __launch_bounds__(256) void transpose_cast(
    const float* __restrict__ W0, const float* __restrict__ W1,
    const float* __restrict__ W2, const float* __restrict__ W3,
    _Float16* __restrict__ T0, _Float16* __restrict__ T1,
    _Float16* __restrict__ T2, _Float16* __restrict__ T3) {
  __shared__ float t[64][65];
  const float* W; _Float16* T;
  switch (blockIdx.z) {
    case 0: W = W0; T = T0; break;
    case 1: W = W1; T = T1; break;
    case 2: W = W2; T = T2; break;
    default: W = W3; T = T3; break;
  }
  const int bx = blockIdx.x;  // k block
  const int by = blockIdx.y;  // n block
  const int tid = threadIdx.x;
  const int c = tid & 15, rr = tid >> 4;
#pragma unroll
  for (int i = 0; i < 4; ++i) {
    int k = rr + i * 16;
    float4 v = *(const float4*)(W + (size_t)(bx * 64 + k) * DM + by * 64 + c * 4);
    t[k][c * 4 + 0] = v.x; t[k][c * 4 + 1] = v.y;
    t[k][c * 4 + 2] = v.z; t[k][c * 4 + 3] = v.w;
  }
  __syncthreads();
#pragma unroll
  for (int i = 0; i < 4; ++i) {
    int n = rr + i * 16;
    half4_t h;
    h[0] = (_Float16)t[c * 4 + 0][n];
    h[1] = (_Float16)t[c * 4 + 1][n];
    h[2] = (_Float16)t[c * 4 + 2][n];
    h[3] = (_Float16)t[c * 4 + 3][n];
    *(half4_t*)(T + (size_t)(by * 64 + n) * DM + bx * 64 + c * 4) = h;
  }
}

// ---------- f16 MFMA GEMM: C[M][1024] = A[M][1024] @ Bt[1024][1024]^T ----------
template <typename OutT>
__device__ __forceinline__ void gemm_mfma_body(const _Float16* __restrict__ A,
                                               const _Float16* __restrict__ Bt,
                                               OutT* __restrict__ C) {
  __shared__ _Float16 As[128 * 32];
  __shared__ _Float16 Bs[128 * 32];
  const int tid = threadIdx.x;
  const int wave = tid >> 6, lane = tid & 63;
  const int wm = wave >> 1, wn = wave & 1;
  const int bm = blockIdx.x * 128, bn = blockIdx.y * 128;
  const int lrow = lane >> 2;       // 0..15 within a 16-row segment
  const int lkb = (lane & 3) * 8;   // k element offset of this lane's 16B
  const int l16 = lane & 15, lq = lane >> 4;
  floatx4 acc[4][4] = {};

  for (int k0 = 0; k0 < DM; k0 += 32) {
    __syncthreads();
#pragma unroll
    for (int s2 = 0; s2 < 2; ++s2) {
      const int seg = wave * 2 + s2;  // 16-row segment of the 128-row tile
      stage16(A + (size_t)(bm + seg * 16 + lrow) * DM + k0 + lkb,
              As + seg * 512, lane);
      stage16(Bt + (size_t)(bn + seg * 16 + lrow) * DM + k0 + lkb,
              Bs + seg * 512, lane);
    }
    __syncthreads();
    half8_t af[4], bf[4];
#pragma unroll
    for (int mi = 0; mi < 4; ++mi)
      af[mi] = *(const half8_t*)(As + (wm * 64 + mi * 16 + l16) * 32 + lq * 8);
#pragma unroll
    for (int ni = 0; ni < 4; ++ni)
      bf[ni] = *(const half8_t*)(Bs + (wn * 64 + ni * 16 + l16) * 32 + lq * 8);
#pragma unroll
    for (int mi = 0; mi < 4; ++mi)
#pragma unroll
      for (int ni = 0; ni < 4; ++ni)
        acc[mi][ni] = __builtin_amdgcn_mfma_f32_16x16x32_f16(
            af[mi], bf[ni], acc[mi][ni], 0, 0, 0);
  }
  // epilogue: C/D layout col=lane&15, row=(lane>>4)*4+reg  [m89-verified]
#pragma unroll
  for (int mi = 0; mi < 4; ++mi)
#pragma unroll
    for (int ni = 0; ni < 4; ++ni) {
      const int col = bn + wn * 64 + ni * 16 + l16;
#pragma unroll
      for (int r = 0; r < 4; ++r) {
        const int row = bm + wm * 64 + mi * 16 + lq * 4 + r;
        C[(size_t)row * DM + col] = (OutT)acc[mi][ni][r];
      }
    }
}

__global__ __launch_bounds__(256) void gemm_qkv_mfma(
    const _Float16* __restrict__ xh, const _Float16* __restrict__ Wt0,
    const _Float16* __restrict__ Wt1, const _Float16* __restrict__ Wt2,
    _Float16* __restrict__ q, _Float16* __restrict__ k,
    _Float16* __restrict__ v) {
  const _Float16* Bt; _Float16* C;
  if (blockIdx.z == 0)      { Bt = Wt0; C = q; }
  else if (blockIdx.z == 1) { Bt = Wt1; C = k; }
  else                      { Bt = Wt2; C = v; }
  gemm_mfma_body<_Float16>(xh, Bt, C);
}

__global__ __launch_bounds__(256) void gemm_out_mfma(
    const _Float16* __restrict__ A, const _Float16* __restrict__ Bt,
    float* __restrict__ C) {
  gemm_mfma_body<float>(A, Bt, C);
}

// ---------- RoPE + w-weighting + layout transform -----------------------
// qh16: fp16, pre-scaled by rsqrt(1+n); kth: fp16 pre-scaled by 0.125*sqrt(1+n)
__global__ __launch_bounds__(256) void transform_kernel(
    const _Float16* __restrict__ q, const _Float16* __restrict__ k,
    const _Float16* __restrict__ v, const float* __restrict__ wre,
    const float* __restrict__ wim, const float* __restrict__ cosT,
    const float* __restrict__ sinT, _Float16* __restrict__ qh16,
    _Float16* __restrict__ kth, _Float16* __restrict__ vth) {
  int idx = blockIdx.x * blockDim.x + threadIdx.x;
  int kk = idx & 31;
  int h  = (idx >> 5) & 15;
  int n  = (idx >> 9) & 2047;
  int b  = idx >> 20;

  size_t base_in = ((size_t)(b * N_SEQ + n)) * DM + h * DH;
  float q_re = (float)q[base_in + 2 * kk], q_im = (float)q[base_in + 2 * kk + 1];
  float k_re = (float)k[base_in + 2 * kk], k_im = (float)k[base_in + 2 * kk + 1];

  float cp = cosT[n * 32 + kk], sp = sinT[n * 32 + kk];

  float qt_re = cp * q_re + sp * q_im;
  float qt_im = cp * q_im - sp * q_re;
  float ktr   = cp * k_re + sp * k_im;
  float kti   = cp * k_im - sp * k_re;

  float wr = wre[kk], wi = wim[kk];
  float qh_re = wr * qt_re - wi * qt_im;
  float qh_im = wr * qt_im + wi * qt_re;

  float sj  = 0.125f * sqrtf(1.0f + (float)n);
  float rsq = rsqrtf(1.0f + (float)n);

  size_t base_out = ((size_t)((b * H_HEADS + h) * N_SEQ + n)) * DH;
  qh16[base_out + kk]      = (_Float16)(qh_re * rsq);
  qh16[base_out + 32 + kk] = (_Float16)(qh_im * rsq);
  kth[base_out + kk]      = (_Float16)(ktr * sj);
  kth[base_out + 32 + kk] = (_Float16)(kti * sj);
  vth[base_out + 2 * kk]     = v[base_in + 2 * kk];
  vth[base_out + 2 * kk + 1] = v[base_in + 2 * kk + 1];
}

// ---------- score GEMM: S (block-packed lower-tri, fp16) = qh16 @ kth^T ------
// grid (136, 8). One 128x128 tile per block, K=64 (2 MFMAs per 16x16 out).
__global__ __launch_bounds__(256) void score_gemm(
    const _Float16* __restrict__ qh16, const _Float16* __restrict__ kth,
    _Float16* __restrict__ Smat, int chunk) {
  __shared__ _Float16 As[128][76];   // padded: conflict-free b128 frag reads
  __shared__ _Float16 Bs[128][76];
  const int x = blockIdx.x;
  int ti = 0;
  while ((ti + 1) * (ti + 2) / 2 <= x) ++ti;
  const int tj = x - (ti * (ti + 1)) / 2;
  const int bhl = blockIdx.y;
  const int bh  = chunk * BH_PER_CHUNK + bhl;
  const int tid = threadIdx.x;
  const int wave = tid >> 6, lane = tid & 63;
  const int wm = wave >> 1, wn = wave & 1;
  const int l16 = lane & 15, lq = lane >> 4;

  const _Float16* qb = qh16 + ((size_t)bh * N_SEQ + (size_t)ti * 128) * DH;
  const _Float16* kb = kth  + ((size_t)bh * N_SEQ + (size_t)tj * 128) * DH;

#pragma unroll
  for (int u = 0; u < 4; ++u) {
    const int idx = u * 256 + tid;  // 1024 chunks of 8 halves per matrix
    const int row = idx >> 3, c8 = idx & 7;
    *(half8_t*)&As[row][c8 * 8] = *(const half8_t*)(qb + (size_t)row * DH + c8 * 8);
    *(half8_t*)&Bs[row][c8 * 8] = *(const half8_t*)(kb + (size_t)row * DH + c8 * 8);
  }
  __syncthreads();

  floatx4 acc[4][4] = {};
#pragma unroll
  for (int mi = 0; mi < 4; ++mi) {
    const half8_t a0 = *(const half8_t*)&As[wm * 64 + mi * 16 + l16][lq * 8];
    const half8_t a1 = *(const half8_t*)&As[wm * 64 + mi * 16 + l16][32 + lq * 8];
#pragma unroll
    for (int ni = 0; ni < 4; ++ni) {
      const half8_t b0 = *(const half8_t*)&Bs[wn * 64 + ni * 16 + l16][lq * 8];
      const half8_t b1 = *(const half8_t*)&Bs[wn * 64 + ni * 16 + l16][32 + lq * 8];
      acc[mi][ni] = __builtin_amdgcn_mfma_f32_16x16x32_f16(a0, b0, acc[mi][ni], 0, 0, 0);
      acc[mi][ni] = __builtin_amdgcn_mfma_f32_16x16x32_f16(a1, b1, acc[mi][ni], 0, 0, 0);
    }
  }

  _Float16* Sblk = Smat + ((size_t)bhl * NTILES + (size_t)x) * TILE_ELEMS;
#pragma unroll
  for (int mi = 0; mi < 4; ++mi)
#pragma unroll
    for (int ni = 0; ni < 4; ++ni) {
      const int col = wn * 64 + ni * 16 + l16;
#pragma unroll
      for (int rr = 0; rr < 4; ++rr) {
        const int row = wm * 64 + mi * 16 + lq * 4 + rr;
        Sblk[row * 128 + col] = (_Float16)acc[mi][ni][rr];
      }
    }
}

// ---------- selection + softmax + AV over materialized scores ----------
// grid (128, 8). 16 rows per block; 16 threads per row on streaming scans.
__global__ __launch_bounds__(256) void select_kernel(
    const _Float16* __restrict__ Smat, const _Float16* __restrict__ vth,
    _Float16* __restrict__ oh, int chunk) {
  __shared__ unsigned list[TQ][LCAP];   // 28 KB candidates (us<<16 | j)
  __shared__ unsigned hist[TQ][128];    // 8 KB packed 2x16-bit counts
  __shared__ unsigned cnt[TQ], tkA[TQ], rowmk[TQ];
  __shared__ int bcut[TQ], bsel[TQ], krem[TQ], rowact[TQ];
  __shared__ int badflag;

  const int tile = 127 - blockIdx.x;    // heavy blocks first
  const int bhl  = blockIdx.y;
  const int bh   = chunk * BH_PER_CHUNK + bhl;
  const int i0   = tile * TQ;
  const int ti   = tile >> 3;           // 0..15 (all 16 rows share tile-row)
  const int tid  = threadIdx.x;
  const int r = tid >> 4, ts = tid & 15;
  const int i = i0 + r, L = i + 1;

  const _Float16* Srow = Smat
      + ((size_t)bhl * NTILES + (size_t)((ti * (ti + 1)) / 2)) * TILE_ELEMS
      + (size_t)(i & 127) * 128;
  const _Float16* vbase = vth + (size_t)bh * N_SEQ * DH;

#pragma unroll
  for (int u = 0; u < 8; ++u) ((unsigned*)hist)[u * 256 + tid] = 0;
  if (tid < TQ) { cnt[tid] = 0; rowact[tid] = 1; rowmk[tid] = 0; }
  __syncthreads();

  // ---- pass A: sampled hi-byte histogram (every 4th tile, fully) ----
  if (L > TOPK) {
    for (int tj = 0; tj <= ti; tj += 4) {
      const half8_t v = *(const half8_t*)(Srow + (size_t)tj * TILE_ELEMS + ts * 8);
#pragma unroll
      for (int e = 0; e < 8; ++e) {
        const int j = tj * 128 + ts * 8 + e;
        if (j <= i) {
          const unsigned hb = okey16(h2us(v[e])) >> 8;
          atomicAdd(&hist[r][hb >> 1], 1u << ((hb & 1) * 16));
        }
      }
    }
  }
  __syncthreads();

  // ---- choose per-row cut byte (target ~212 expected candidates) ----
  if (tid < TQ) {
    int b = 0;
    const int ir = i0 + tid, Lr = ir + 1;
    if (Lr > TOPK) {
      int samp = 0;
      for (int tj = 0; tj <= ti; tj += 4) {
        int c = Lr - tj * 128;
        if (c > 0) samp += (c > 128 ? 128 : c);
      }
      const float f = (float)samp / (float)Lr;
      int C = (int)ceilf(f * (100.0f + 150.0f * (1.0f - f)));
      if (C < 1) C = 1;
      int cum = 0;
      for (b = 255; b >= 1; --b) {
        cum += (int)((hist[tid][b >> 1] >> ((b & 1) * 16)) & 0xffffu);
        if (cum >= C) break;
      }
      if (b < 1) b = 0;
    }
    bcut[tid] = b;
  }
  __syncthreads();

  // ---- pass B: full scan collect; robust per-row retries ----
  for (int attempt = 0;; ++attempt) {
    if (rowact[r]) {
      const int bc = bcut[r];
      for (int tj = 0; tj <= ti; ++tj) {
        const half8_t v = *(const half8_t*)(Srow + (size_t)tj * TILE_ELEMS + ts * 8);
#pragma unroll
        for (int e = 0; e < 8; ++e) {
          const int j = tj * 128 + ts * 8 + e;
          if (j <= i) {
            const unsigned short us = h2us(v[e]);
            const unsigned key = okey16(us);
            if ((int)(key >> 8) >= bc) {
              const unsigned pos = atomicAdd(&cnt[r], 1u);
              if (pos < LCAP) list[r][pos] = ((unsigned)us << 16) | (unsigned)j;
            }
          }
        }
      }
    }
    __syncthreads();
    if (tid == 0) badflag = 0;
    __syncthreads();
    if (tid < TQ && rowact[tid]) {
      const int Lr = i0 + tid + 1;
      const unsigned c = cnt[tid];
      const bool over  = c > (unsigned)LCAP;
      const bool under = (Lr > TOPK) && (c < (unsigned)TOPK);
      if ((over || under) && attempt < 3) {
        int b = bcut[tid];
        if (over) { if (b < 255) ++b; }
        else      { b -= 2; if (b < 0) b = 0; }
        bcut[tid] = b;
        cnt[tid] = 0;          // safe: another collection WILL run
        badflag = 1;
      } else {
        rowact[tid] = 0;       // accept list (possibly truncated/short)
      }
    }
    __syncthreads();
    if (!badflag) break;
  }

  // ---- exact threshold via 2-level radix over the small list ----
#pragma unroll
  for (int u = 0; u < 8; ++u) ((unsigned*)hist)[u * 256 + tid] = 0;
  __syncthreads();
  {
    const int n = (int)min(cnt[r], (unsigned)LCAP);
    unsigned km = 0;
    for (int s = ts; s < n; s += 16) {
      const unsigned key = okey16((unsigned short)(list[r][s] >> 16));
      km = km > key ? km : key;
      const unsigned hb = key >> 8;
      atomicAdd(&hist[r][hb >> 1], 1u << ((hb & 1) * 16));
    }
#pragma unroll
    for (int g = 1; g <= 8; g <<= 1) {
      const unsigned o = (unsigned)__shfl_xor((int)km, g);
      km = km > o ? km : o;
    }
    if (ts == 0) rowmk[r] = km;
  }
  __syncthreads();
  if (tid < TQ) {
    const int Lr = i0 + tid + 1;
    int bs = -1, kr = 0;
    if (Lr > TOPK && cnt[tid] >= (unsigned)TOPK) {
      int cum = 0;
      for (int b = 255; b >= 0; --b) {
        const int h = (int)((hist[tid][b >> 1] >> ((b & 1) * 16)) & 0xffffu);
        if (cum + h >= TOPK) { bs = b; kr = TOPK - cum; break; }
        cum += h;
      }
    }
    bsel[tid] = bs; krem[tid] = kr;
  }
  __syncthreads();
#pragma unroll
  for (int u = 0; u < 8; ++u) ((unsigned*)hist)[u * 256 + tid] = 0;
  __syncthreads();
  {
    const int bs = bsel[r];
    if (bs >= 0) {
      const int n = (int)min(cnt[r], (unsigned)LCAP);
      for (int s = ts; s < n; s += 16) {
        const unsigned key = okey16((unsigned short)(list[r][s] >> 16));
        if ((int)(key >> 8) == bs)
          atomicAdd(&hist[r][(key & 255u) >> 1], 1u << ((key & 1) * 16));
      }
    }
  }
  __syncthreads();
  if (tid < TQ) {
    unsigned tk = 0;
    const int bs = bsel[tid];
    if (bs >= 0) {
      int cum = 0, b = 255;
      const int kr = krem[tid];
      for (; b >= 0; --b) {
        const int h = (int)((hist[tid][b >> 1] >> ((b & 1) * 16)) & 0xffffu);
        if (cum + h >= kr) break;
        cum += h;
      }
      if (b < 0) b = 0;
      tk = ((unsigned)bs << 8) | (unsigned)b;
    }
    tkA[tid] = tk;
  }
  __syncthreads();

  // ---- fused filter + softmax + sparse AV (one wave per row) ----
  const int wv = tid >> 6, lane = tid & 63;
  for (int rr = wv; rr < TQ; rr += 4) {
    const int n = (int)min(cnt[rr], (unsigned)LCAP);
    const unsigned mk = rowmk[rr];
    const float m = (float)us2h((mk >= 0x8000u) ? (unsigned short)(mk & 0x7fffu)
                                                : (unsigned short)(~mk));
    const unsigned tk = tkA[rr];
    float acc = 0.f, psum = 0.f;
    for (int s = 0; s < n; ++s) {
      const unsigned e = list[rr][s];
      const unsigned short us = (unsigned short)(e >> 16);
      if (okey16(us) >= tk) {  // wave-uniform branch
        const float p = expf((float)us2h(us) - m);
        psum += p;
        acc += p * (float)vbase[(size_t)(e & 0xffffu) * DH + lane];
      }
    }
    const float inv = (psum > 0.f) ? 1.0f / psum : 0.f;  // NaN guard
    const int b = bh >> 4, h = bh & 15;
    const int ii = i0 + rr;
    oh[((size_t)(b * N_SEQ + ii)) * DM + h * DH + lane] = (_Float16)(acc * inv);
  }
}

// ---------- launch ----------
extern "C" void kernel_launch(void* const* d_in, const int* in_sizes, int n_in,
                              void* d_out, int out_size, void* d_ws, size_t ws_size,
                              hipStream_t stream) {
  const float* x  = (const float*)d_in[0];
  const float* Wq = (const float*)d_in[1];
  const float* Wk = (const float*)d_in[2];
  const float* Wv = (const float*)d_in[3];
  const float* Wo = (const float*)d_in[4];
  float* out = (float*)d_out;
  char* ws = (char*)d_ws;

  const size_t MAT = (size_t)B_SZ * N_SEQ * DM;  // 4,194,304 elements
  const size_t WSZ = (size_t)DM * DM;            // 1,048,576

  _Float16* qh16 = (_Float16*)ws;                    ws += MAT * 2;   // 8 MB
  _Float16* xh   = (_Float16*)ws;                    ws += MAT * 2;   // 8 MB
  _Float16* kth  = (_Float16*)ws;                    ws += MAT * 2;
  _Float16* vth  = (_Float16*)ws;                    ws += MAT * 2;
  _Float16* Wt0  = (_Float16*)ws;                    ws += WSZ * 2;
  _Float16* Wt1  = (_Float16*)ws;                    ws += WSZ * 2;
  _Float16* Wt2  = (_Float16*)ws;                    ws += WSZ * 2;
  _Float16* Wt3  = (_Float16*)ws;                    ws += WSZ * 2;
  float*    wre  = (float*)ws;                       ws += KC * 4;
  float*    wim  = (float*)ws;                       ws += KC * 4;
  float*    cosT = (float*)ws;                       ws += (size_t)N_SEQ * KC * 4;
  float*    sinT = (float*)ws;                       ws += (size_t)N_SEQ * KC * 4;
  // Smat (35.7 MB) overlaps qf/kf/vf (24 MB): qf/kf/vf die before score_gemm.
  _Float16* Smat = (_Float16*)ws;   // spans qf,kf,vf + tail
  _Float16* qf   = (_Float16*)ws;                    ws += MAT * 2;
  _Float16* kf   = (_Float16*)ws;                    ws += MAT * 2;
  _Float16* vf   = (_Float16*)ws;                    ws += MAT * 2;
  ws += (size_t)BH_PER_CHUNK * NTILES * TILE_ELEMS * 2 - 3 * MAT * 2;  // Smat tail
  _Float16* oh   = xh;  // xh dead after QKV GEMM; reuse for attn output

  const_kernel<<<1, 32, 0, stream>>>(wre, wim);
  rope_kernel<<<(N_SEQ * KC) / 256, 256, 0, stream>>>(cosT, sinT);
  cast_x<<<(int)(MAT / 4 / 256), 256, 0, stream>>>(x, xh);
  transpose_cast<<<dim3(16, 16, 4), 256, 0, stream>>>(Wq, Wk, Wv, Wo,
                                                      Wt0, Wt1, Wt2, Wt3);
  gemm_qkv_mfma<<<dim3(32, 8, 3), 256, 0, stream>>>(xh, Wt0, Wt1, Wt2,
                                                    qf, kf, vf);
  transform_kernel<<<(B_SZ * N_SEQ * H_HEADS * KC) / 256, 256, 0, stream>>>(
      qf, kf, vf, wre, wim, cosT, sinT, qh16, kth, vth);
  for (int c = 0; c < NCHUNK; ++c) {
    score_gemm<<<dim3(NTILES, BH_PER_CHUNK), 256, 0, stream>>>(qh16, kth, Smat, c);
    select_kernel<<<dim3(128, BH_PER_CHUNK), 256, 0, stream>>>(Smat, vth, oh, c);
  }
  gemm_out_mfma<<<dim3(32, 8, 1), 256, 0, stream>>>(oh, Wt3, out);
}

// Round 11
// 754.540 us; speedup vs baseline: 1.5092x; 1.5092x over previous
//
#include <hip/hip_runtime.h>
#include <math.h>

#define B_SZ 2
#define N_SEQ 2048
#define DM 1024
#define H_HEADS 16
#define DH 64
#define KC 32
#define TOPK 100
#define TQ 16
#define LCAP 448
#define FCAP 160
#define NCHUNK 4
#define BH_PER_CHUNK 8
#define NTILES 136   // 16*17/2 lower-triangular 128x128 tiles
#define TILE_ELEMS 16384

typedef _Float16 half2_t __attribute__((ext_vector_type(2)));
typedef _Float16 half4_t __attribute__((ext_vector_type(4)));
typedef _Float16 half8_t __attribute__((ext_vector_type(8)));
typedef float floatx4 __attribute__((ext_vector_type(4)));

// ---------- helpers ----------
__device__ __forceinline__ unsigned short h2us(_Float16 h) {
  unsigned short u; __builtin_memcpy(&u, &h, 2); return u;
}
__device__ __forceinline__ _Float16 us2h(unsigned short u) {
  _Float16 h; __builtin_memcpy(&h, &u, 2); return h;
}
__device__ __forceinline__ unsigned okey16(unsigned short us) {
  return (us & 0x8000u) ? (unsigned)(unsigned short)~us
                        : (unsigned)(us | 0x8000u);
}
__device__ __forceinline__ float key2f(unsigned mk) {
  return (float)us2h((mk & 0x8000u) ? (unsigned short)(mk & 0x7fffu)
                                    : (unsigned short)(~mk));
}

// async global->LDS, 16 B per lane; lds_base must be wave-uniform
__device__ __forceinline__ void stage16(const _Float16* g, _Float16* lds_base,
                                        int lane) {
#if __has_builtin(__builtin_amdgcn_global_load_lds)
  __builtin_amdgcn_global_load_lds(
      (const __attribute__((address_space(1))) void*)g,
      (__attribute__((address_space(3))) void*)lds_base, 16, 0, 0);
#else
  *(half8_t*)(lds_base + lane * 8) = *(const half8_t*)g;
#endif
}

// ---------- constants: Riemann-zero weights ----------
__global__ void const_kernel(float* __restrict__ wre, float* __restrict__ wim) {
  __shared__ double g0s;
  const int k = threadIdx.x;  // 32 threads
  const double PI = 3.14159265358979323846;
  const double E_ = 2.71828182845904523536;
  double n = (double)(k + 1);
  double t = 10.0 + 6.0 * n;
  for (int it = 0; it < 60; ++it) {
    double f  = t / (2.0 * PI) * log(t / (2.0 * PI * E_)) - (n - 0.875);
    double fp = log(t / (2.0 * PI)) / (2.0 * PI);
    t = t - f / fp;
  }
  if (k == 0) g0s = t;
  __syncthreads();
  double g = t / g0s;
  double denom = 0.25 + g * g;
  wre[k] = (float)(0.5 / denom);
  wim[k] = (float)(-g / denom);
}

// ---------- RoPE tables ----------
__global__ __launch_bounds__(256) void rope_kernel(float* __restrict__ cosT,
                                                   float* __restrict__ sinT) {
  int idx = blockIdx.x * 256 + threadIdx.x;  // 65536 = 2048*32
  int kk = idx & 31, n = idx >> 5;
  double inv_freq = pow(10000.0, -(double)kk / 32.0);
  double ph = (double)n * inv_freq;
  cosT[idx] = (float)cos(ph);
  sinT[idx] = (float)sin(ph);
}

// ---------- cast x fp32 -> fp16 ----------
__global__ __launch_bounds__(256) void cast_x(const float* __restrict__ x,
                                              _Float16* __restrict__ xh) {
  int idx = blockIdx.x * 256 + threadIdx.x;
  float4 v = ((const float4*)x)[idx];
  half4_t h;
  h[0] = (_Float16)v.x; h[1] = (_Float16)v.y;
  h[2] = (_Float16)v.z; h[3] = (_Float16)v.w;
  ((half4_t*)xh)[idx] = h;
}

// ---------- transpose-cast W (fp32 [k][n]) -> Wt (fp16 [n][k]) ----------
__global__ __launch_bounds__(256) void transpose_cast(
    const float* __restrict__ W0, const float* __restrict__ W1,
    const float* __restrict__ W2, const float* __restrict__ W3,
    _Float16* __restrict__ T0, _Float16* __restrict__ T1,
    _Float16* __restrict__ T2, _Float16* __restrict__ T3) {
  __shared__ float t[64][65];
  const float* W; _Float16* T;
  switch (blockIdx.z) {
    case 0: W = W0; T = T0; break;
    case 1: W = W1; T = T1; break;
    case 2: W = W2; T = T2; break;
    default: W = W3; T = T3; break;
  }
  const int bx = blockIdx.x;  // k block
  const int by = blockIdx.y;  // n block
  const int tid = threadIdx.x;
  const int c = tid & 15, rr = tid >> 4;
#pragma unroll
  for (int i = 0; i < 4; ++i) {
    int k = rr + i * 16;
    float4 v = *(const float4*)(W + (size_t)(bx * 64 + k) * DM + by * 64 + c * 4);
    t[k][c * 4 + 0] = v.x; t[k][c * 4 + 1] = v.y;
    t[k][c * 4 + 2] = v.z; t[k][c * 4 + 3] = v.w;
  }
  __syncthreads();
#pragma unroll
  for (int i = 0; i < 4; ++i) {
    int n = rr + i * 16;
    half4_t h;
    h[0] = (_Float16)t[c * 4 + 0][n];
    h[1] = (_Float16)t[c * 4 + 1][n];
    h[2] = (_Float16)t[c * 4 + 2][n];
    h[3] = (_Float16)t[c * 4 + 3][n];
    *(half4_t*)(T + (size_t)(by * 64 + n) * DM + bx * 64 + c * 4) = h;
  }
}

// ---------- f16 MFMA GEMM: C[M][1024] = A[M][1024] @ Bt[1024][1024]^T ----------
template <typename OutT>
__device__ __forceinline__ void gemm_mfma_body(const _Float16* __restrict__ A,
                                               const _Float16* __restrict__ Bt,
                                               OutT* __restrict__ C) {
  __shared__ _Float16 As[128 * 32];
  __shared__ _Float16 Bs[128 * 32];
  const int tid = threadIdx.x;
  const int wave = tid >> 6, lane = tid & 63;
  const int wm = wave >> 1, wn = wave & 1;
  const int bm = blockIdx.x * 128, bn = blockIdx.y * 128;
  const int lrow = lane >> 2;       // 0..15 within a 16-row segment
  const int lkb = (lane & 3) * 8;   // k element offset of this lane's 16B
  const int l16 = lane & 15, lq = lane >> 4;
  floatx4 acc[4][4] = {};

  for (int k0 = 0; k0 < DM; k0 += 32) {
    __syncthreads();
#pragma unroll
    for (int s2 = 0; s2 < 2; ++s2) {
      const int seg = wave * 2 + s2;  // 16-row segment of the 128-row tile
      stage16(A + (size_t)(bm + seg * 16 + lrow) * DM + k0 + lkb,
              As + seg * 512, lane);
      stage16(Bt + (size_t)(bn + seg * 16 + lrow) * DM + k0 + lkb,
              Bs + seg * 512, lane);
    }
    __syncthreads();
    half8_t af[4], bf[4];
#pragma unroll
    for (int mi = 0; mi < 4; ++mi)
      af[mi] = *(const half8_t*)(As + (wm * 64 + mi * 16 + l16) * 32 + lq * 8);
#pragma unroll
    for (int ni = 0; ni < 4; ++ni)
      bf[ni] = *(const half8_t*)(Bs + (wn * 64 + ni * 16 + l16) * 32 + lq * 8);
#pragma unroll
    for (int mi = 0; mi < 4; ++mi)
#pragma unroll
      for (int ni = 0; ni < 4; ++ni)
        acc[mi][ni] = __builtin_amdgcn_mfma_f32_16x16x32_f16(
            af[mi], bf[ni], acc[mi][ni], 0, 0, 0);
  }
  // epilogue: C/D layout col=lane&15, row=(lane>>4)*4+reg  [m89-verified]
#pragma unroll
  for (int mi = 0; mi < 4; ++mi)
#pragma unroll
    for (int ni = 0; ni < 4; ++ni) {
      const int col = bn + wn * 64 + ni * 16 + l16;
#pragma unroll
      for (int r = 0; r < 4; ++r) {
        const int row = bm + wm * 64 + mi * 16 + lq * 4 + r;
        C[(size_t)row * DM + col] = (OutT)acc[mi][ni][r];
      }
    }
}

__global__ __launch_bounds__(256) void gemm_qkv_mfma(
    const _Float16* __restrict__ xh, const _Float16* __restrict__ Wt0,
    const _Float16* __restrict__ Wt1, const _Float16* __restrict__ Wt2,
    _Float16* __restrict__ q, _Float16* __restrict__ k,
    _Float16* __restrict__ v) {
  const _Float16* Bt; _Float16* C;
  if (blockIdx.z == 0)      { Bt = Wt0; C = q; }
  else if (blockIdx.z == 1) { Bt = Wt1; C = k; }
  else                      { Bt = Wt2; C = v; }
  gemm_mfma_body<_Float16>(xh, Bt, C);
}

__global__ __launch_bounds__(256) void gemm_out_mfma(
    const _Float16* __restrict__ A, const _Float16* __restrict__ Bt,
    float* __restrict__ C) {
  gemm_mfma_body<float>(A, Bt, C);
}

// ---------- RoPE + w-weighting + layout transform -----------------------
// qh16: fp16, pre-scaled by rsqrt(1+n); kth: fp16 pre-scaled by 0.125*sqrt(1+n)
__global__ __launch_bounds__(256) void transform_kernel(
    const _Float16* __restrict__ q, const _Float16* __restrict__ k,
    const _Float16* __restrict__ v, const float* __restrict__ wre,
    const float* __restrict__ wim, const float* __restrict__ cosT,
    const float* __restrict__ sinT, _Float16* __restrict__ qh16,
    _Float16* __restrict__ kth, _Float16* __restrict__ vth) {
  int idx = blockIdx.x * blockDim.x + threadIdx.x;
  int kk = idx & 31;
  int h  = (idx >> 5) & 15;
  int n  = (idx >> 9) & 2047;
  int b  = idx >> 20;

  size_t base_in = ((size_t)(b * N_SEQ + n)) * DM + h * DH;
  float q_re = (float)q[base_in + 2 * kk], q_im = (float)q[base_in + 2 * kk + 1];
  float k_re = (float)k[base_in + 2 * kk], k_im = (float)k[base_in + 2 * kk + 1];

  float cp = cosT[n * 32 + kk], sp = sinT[n * 32 + kk];

  float qt_re = cp * q_re + sp * q_im;
  float qt_im = cp * q_im - sp * q_re;
  float ktr   = cp * k_re + sp * k_im;
  float kti   = cp * k_im - sp * k_re;

  float wr = wre[kk], wi = wim[kk];
  float qh_re = wr * qt_re - wi * qt_im;
  float qh_im = wr * qt_im + wi * qt_re;

  float sj  = 0.125f * sqrtf(1.0f + (float)n);
  float rsq = rsqrtf(1.0f + (float)n);

  size_t base_out = ((size_t)((b * H_HEADS + h) * N_SEQ + n)) * DH;
  qh16[base_out + kk]      = (_Float16)(qh_re * rsq);
  qh16[base_out + 32 + kk] = (_Float16)(qh_im * rsq);
  kth[base_out + kk]      = (_Float16)(ktr * sj);
  kth[base_out + 32 + kk] = (_Float16)(kti * sj);
  vth[base_out + 2 * kk]     = v[base_in + 2 * kk];
  vth[base_out + 2 * kk + 1] = v[base_in + 2 * kk + 1];
}

// ---------- score GEMM: S (block-packed lower-tri, fp16) = qh16 @ kth^T ------
// grid (136, 8). One 128x128 tile per block, K=64 (2 MFMAs per 16x16 out).
__global__ __launch_bounds__(256) void score_gemm(
    const _Float16* __restrict__ qh16, const _Float16* __restrict__ kth,
    _Float16* __restrict__ Smat, int chunk) {
  __shared__ _Float16 As[128][76];   // padded: conflict-free b128 frag reads
  __shared__ _Float16 Bs[128][76];
  const int x = blockIdx.x;
  int ti = 0;
  while ((ti + 1) * (ti + 2) / 2 <= x) ++ti;
  const int tj = x - (ti * (ti + 1)) / 2;
  const int bhl = blockIdx.y;
  const int bh  = chunk * BH_PER_CHUNK + bhl;
  const int tid = threadIdx.x;
  const int wave = tid >> 6, lane = tid & 63;
  const int wm = wave >> 1, wn = wave & 1;
  const int l16 = lane & 15, lq = lane >> 4;

  const _Float16* qb = qh16 + ((size_t)bh * N_SEQ + (size_t)ti * 128) * DH;
  const _Float16* kb = kth  + ((size_t)bh * N_SEQ + (size_t)tj * 128) * DH;

#pragma unroll
  for (int u = 0; u < 4; ++u) {
    const int idx = u * 256 + tid;  // 1024 chunks of 8 halves per matrix
    const int row = idx >> 3, c8 = idx & 7;
    *(half8_t*)&As[row][c8 * 8] = *(const half8_t*)(qb + (size_t)row * DH + c8 * 8);
    *(half8_t*)&Bs[row][c8 * 8] = *(const half8_t*)(kb + (size_t)row * DH + c8 * 8);
  }
  __syncthreads();

  floatx4 acc[4][4] = {};
#pragma unroll
  for (int mi = 0; mi < 4; ++mi) {
    const half8_t a0 = *(const half8_t*)&As[wm * 64 + mi * 16 + l16][lq * 8];
    const half8_t a1 = *(const half8_t*)&As[wm * 64 + mi * 16 + l16][32 + lq * 8];
#pragma unroll
    for (int ni = 0; ni < 4; ++ni) {
      const half8_t b0 = *(const half8_t*)&Bs[wn * 64 + ni * 16 + l16][lq * 8];
      const half8_t b1 = *(const half8_t*)&Bs[wn * 64 + ni * 16 + l16][32 + lq * 8];
      acc[mi][ni] = __builtin_amdgcn_mfma_f32_16x16x32_f16(a0, b0, acc[mi][ni], 0, 0, 0);
      acc[mi][ni] = __builtin_amdgcn_mfma_f32_16x16x32_f16(a1, b1, acc[mi][ni], 0, 0, 0);
    }
  }

  _Float16* Sblk = Smat + ((size_t)bhl * NTILES + (size_t)x) * TILE_ELEMS;
#pragma unroll
  for (int mi = 0; mi < 4; ++mi)
#pragma unroll
    for (int ni = 0; ni < 4; ++ni) {
      const int col = wn * 64 + ni * 16 + l16;
#pragma unroll
      for (int rr = 0; rr < 4; ++rr) {
        const int row = wm * 64 + mi * 16 + lq * 4 + rr;
        Sblk[row * 128 + col] = (_Float16)acc[mi][ni][rr];
      }
    }
}

// ---------- selection + softmax + AV over materialized scores ----------
// grid (128, 8). 16 rows/block; exact hi-byte cut (no retries); compacted AV.
__global__ __launch_bounds__(256) void select_kernel(
    const _Float16* __restrict__ Smat, const _Float16* __restrict__ vth,
    _Float16* __restrict__ oh, int chunk) {
  __shared__ unsigned list[TQ][LCAP];       // 28 KB candidates (us<<16 | j)
  __shared__ unsigned hist[TQ][128];        // 8 KB packed 2x16-bit counts
  __shared__ float pf[TQ][FCAP];            // 10 KB survivor p-values
  __shared__ unsigned short jf[TQ][FCAP];   // 5 KB survivor indices
  __shared__ float rowsum[TQ];
  __shared__ unsigned cnt[TQ], cnt2[TQ], tkA[TQ], rowmk[TQ];
  __shared__ int bsel[TQ], krem[TQ], rowact[TQ];
  __shared__ int badflag;

  const int tile = 127 - blockIdx.x;    // heavy blocks first
  const int bhl  = blockIdx.y;
  const int bh   = chunk * BH_PER_CHUNK + bhl;
  const int i0   = tile * TQ;
  const int ti   = tile >> 3;           // 0..15 (all 16 rows share tile-row)
  const int tid  = threadIdx.x;
  const int r = tid >> 4, ts = tid & 15;
  const int i = i0 + r, L = i + 1;

  const _Float16* Srow = Smat
      + ((size_t)bhl * NTILES + (size_t)((ti * (ti + 1)) / 2)) * TILE_ELEMS
      + (size_t)(i & 127) * 128;
  const _Float16* vbase = vth + (size_t)bh * N_SEQ * DH;

#pragma unroll
  for (int u = 0; u < 8; ++u) ((unsigned*)hist)[u * 256 + tid] = 0;
  if (tid < TQ) { cnt[tid] = 0; cnt2[tid] = 0; rowmk[tid] = 0; rowact[tid] = 0; }
  __syncthreads();

  // ---- pass 1: exact hi-byte histogram (full scan) ----
  if (L > TOPK) {
    for (int tj = 0; tj <= ti; ++tj) {
      const half8_t v = *(const half8_t*)(Srow + (size_t)tj * TILE_ELEMS + ts * 8);
#pragma unroll
      for (int e = 0; e < 8; ++e) {
        const int j = tj * 128 + ts * 8 + e;
        if (j <= i) {
          const unsigned hb = okey16(h2us(v[e])) >> 8;
          atomicAdd(&hist[r][hb >> 1], 1u << ((hb & 1) * 16));
        }
      }
    }
  }
  __syncthreads();

  // ---- exact hi cut ----
  if (tid < TQ) {
    const int Lr = i0 + tid + 1;
    int bs = -1, kr = 0;
    if (Lr > TOPK) {
      int cum = 0;
      for (int b = 255; b >= 0; --b) {
        const int h = (int)((hist[tid][b >> 1] >> ((b & 1) * 16)) & 0xffffu);
        if (cum + h >= TOPK) { bs = b; kr = TOPK - cum; break; }
        cum += h;
      }
      if (bs < 0) bs = 0;
    }
    bsel[tid] = bs; krem[tid] = kr;
  }
  __syncthreads();
#pragma unroll
  for (int u = 0; u < 8; ++u) ((unsigned*)hist)[u * 256 + tid] = 0;
  __syncthreads();

  // ---- pass 2: collect candidates (hi >= bsel) + lo-hist (hi == bsel) ----
  {
    const int bs = bsel[r];
    for (int tj = 0; tj <= ti; ++tj) {
      const half8_t v = *(const half8_t*)(Srow + (size_t)tj * TILE_ELEMS + ts * 8);
#pragma unroll
      for (int e = 0; e < 8; ++e) {
        const int j = tj * 128 + ts * 8 + e;
        if (j <= i) {
          const unsigned short us = h2us(v[e]);
          const unsigned key = okey16(us);
          const int hb = (int)(key >> 8);
          if (bs < 0 || hb >= bs) {
            const unsigned pos = atomicAdd(&cnt[r], 1u);
            if (pos < LCAP) list[r][pos] = ((unsigned)us << 16) | (unsigned)j;
            atomicMax(&rowmk[r], key);
            if (hb == bs)
              atomicAdd(&hist[r][(key & 255u) >> 1], 1u << ((key & 1) * 16));
          }
        }
      }
    }
  }
  __syncthreads();

  // ---- exact threshold key from lo-hist ----
  if (tid < TQ) {
    unsigned tk = 0;
    const int bs = bsel[tid];
    if (bs >= 0) {
      int cum = 0, b = 255;
      const int kr = krem[tid];
      for (; b >= 0; --b) {
        const int h = (int)((hist[tid][b >> 1] >> ((b & 1) * 16)) & 0xffffu);
        if (cum + h >= kr) break;
        cum += h;
      }
      if (b < 0) b = 0;
      tk = ((unsigned)bs << 8) | (unsigned)b;
    }
    tkA[tid] = tk;
  }
  __syncthreads();

  // ---- rare overflow: one exact-threshold rescan for rows with cnt > LCAP --
  if (tid == 0) badflag = 0;
  __syncthreads();
  if (tid < TQ && cnt[tid] > (unsigned)LCAP) {
    rowact[tid] = 1; cnt[tid] = 0; badflag = 1;
  }
  __syncthreads();
  if (badflag) {
    if (rowact[r]) {
      const unsigned tk = tkA[r];
      for (int tj = 0; tj <= ti; ++tj) {
        const half8_t v = *(const half8_t*)(Srow + (size_t)tj * TILE_ELEMS + ts * 8);
#pragma unroll
        for (int e = 0; e < 8; ++e) {
          const int j = tj * 128 + ts * 8 + e;
          if (j <= i) {
            const unsigned short us = h2us(v[e]);
            if (okey16(us) >= tk) {
              const unsigned pos = atomicAdd(&cnt[r], 1u);
              if (pos < LCAP) list[r][pos] = ((unsigned)us << 16) | (unsigned)j;
            }
          }
        }
      }
    }
    __syncthreads();
  }

  // ---- compact: filter >= tk, p = exp(s - m), store (p, j) ----
  {
    const unsigned tk = tkA[r];
    const float m = key2f(rowmk[r]);
    const int n = (int)min(cnt[r], (unsigned)LCAP);
    float lsum = 0.f;
    for (int s = ts; s < n; s += 16) {
      const unsigned e = list[r][s];
      const unsigned short us = (unsigned short)(e >> 16);
      if (okey16(us) >= tk) {
        const float p = expf((float)us2h(us) - m);
        lsum += p;
        const unsigned pos = atomicAdd(&cnt2[r], 1u);
        if (pos < FCAP) { pf[r][pos] = p; jf[r][pos] = (unsigned short)(e & 0xffffu); }
      }
    }
#pragma unroll
    for (int g = 1; g <= 8; g <<= 1) lsum += __shfl_xor(lsum, g);
    if (ts == 0) rowsum[r] = lsum;
  }
  __syncthreads();

  // ---- AV over compacted survivors, one wave per row ----
  const int wv = tid >> 6, lane = tid & 63;
  for (int rr = wv; rr < TQ; rr += 4) {
    const int n = (int)min(cnt2[rr], (unsigned)FCAP);
    const float sum = rowsum[rr];
    const float inv = (sum > 0.f) ? 1.0f / sum : 0.f;  // NaN guard
    float acc = 0.f;
    for (int s = 0; s < n; ++s)
      acc += pf[rr][s] * (float)vbase[(size_t)jf[rr][s] * DH + lane];
    const int b = bh >> 4, h = bh & 15;
    const int ii = i0 + rr;
    oh[((size_t)(b * N_SEQ + ii)) * DM + h * DH + lane] = (_Float16)(acc * inv);
  }
}

// ---------- launch ----------
extern "C" void kernel_launch(void* const* d_in, const int* in_sizes, int n_in,
                              void* d_out, int out_size, void* d_ws, size_t ws_size,
                              hipStream_t stream) {
  const float* x  = (const float*)d_in[0];
  const float* Wq = (const float*)d_in[1];
  const float* Wk = (const float*)d_in[2];
  const float* Wv = (const float*)d_in[3];
  const float* Wo = (const float*)d_in[4];
  float* out = (float*)d_out;
  char* ws = (char*)d_ws;

  const size_t MAT = (size_t)B_SZ * N_SEQ * DM;  // 4,194,304 elements
  const size_t WSZ = (size_t)DM * DM;            // 1,048,576

  _Float16* qh16 = (_Float16*)ws;                    ws += MAT * 2;   // 8 MB
  _Float16* xh   = (_Float16*)ws;                    ws += MAT * 2;   // 8 MB
  _Float16* kth  = (_Float16*)ws;                    ws += MAT * 2;
  _Float16* vth  = (_Float16*)ws;                    ws += MAT * 2;
  _Float16* Wt0  = (_Float16*)ws;                    ws += WSZ * 2;
  _Float16* Wt1  = (_Float16*)ws;                    ws += WSZ * 2;
  _Float16* Wt2  = (_Float16*)ws;                    ws += WSZ * 2;
  _Float16* Wt3  = (_Float16*)ws;                    ws += WSZ * 2;
  float*    wre  = (float*)ws;                       ws += KC * 4;
  float*    wim  = (float*)ws;                       ws += KC * 4;
  float*    cosT = (float*)ws;                       ws += (size_t)N_SEQ * KC * 4;
  float*    sinT = (float*)ws;                       ws += (size_t)N_SEQ * KC * 4;
  // Smat (35.7 MB) overlaps qf/kf/vf (24 MB): qf/kf/vf die before score_gemm.
  _Float16* Smat = (_Float16*)ws;   // spans qf,kf,vf + tail
  _Float16* qf   = (_Float16*)ws;                    ws += MAT * 2;
  _Float16* kf   = (_Float16*)ws;                    ws += MAT * 2;
  _Float16* vf   = (_Float16*)ws;                    ws += MAT * 2;
  ws += (size_t)BH_PER_CHUNK * NTILES * TILE_ELEMS * 2 - 3 * MAT * 2;  // Smat tail
  _Float16* oh   = xh;  // xh dead after QKV GEMM; reuse for attn output

  const_kernel<<<1, 32, 0, stream>>>(wre, wim);
  rope_kernel<<<(N_SEQ * KC) / 256, 256, 0, stream>>>(cosT, sinT);
  cast_x<<<(int)(MAT / 4 / 256), 256, 0, stream>>>(x, xh);
  transpose_cast<<<dim3(16, 16, 4), 256, 0, stream>>>(Wq, Wk, Wv, Wo,
                                                      Wt0, Wt1, Wt2, Wt3);
  gemm_qkv_mfma<<<dim3(32, 8, 3), 256, 0, stream>>>(xh, Wt0, Wt1, Wt2,
                                                    qf, kf, vf);
  transform_kernel<<<(B_SZ * N_SEQ * H_HEADS * KC) / 256, 256, 0, stream>>>(
      qf, kf, vf, wre, wim, cosT, sinT, qh16, kth, vth);
  for (int c = 0; c < NCHUNK; ++c) {
    score_gemm<<<dim3(NTILES, BH_PER_CHUNK), 256, 0, stream>>>(qh16, kth, Smat, c);
    select_kernel<<<dim3(128, BH_PER_CHUNK), 256, 0, stream>>>(Smat, vth, oh, c);
  }
  gemm_out_mfma<<<dim3(32, 8, 1), 256, 0, stream>>>(oh, Wt3, out);
}